// Round 1
// baseline (7809.287 us; speedup 1.0000x reference)
//
#include <hip/hip_runtime.h>

#define B_ 4
#define T_ 1024
#define D_ 1024
#define N_ 16
#define H_ 64

// ---------------------------------------------------------------------------
// tanh(x) = 1 - 2/(exp(2x)+1); stable at both ends (exp->0 => -1, exp->inf => 1)
__device__ __forceinline__ float fast_tanh(float x) {
  float e = __expf(2.0f * x);
  return 1.0f - 2.0f / (e + 1.0f);
}

// ---------------------------------------------------------------------------
// Mask expand: key_padding_mask may arrive as 1-byte bools or 4-byte ints.
// Detect deterministically: if any byte at index i with i%4!=0 is nonzero over
// the first n bytes, it's 1-byte layout (with ~410 true values among 4096,
// the all-zero case for byte layout is impossible for this fixed input).
__global__ void mask_expand_kernel(const unsigned char* __restrict__ raw,
                                   int* __restrict__ mout, int n) {
  __shared__ int s_flag;
  if (threadIdx.x == 0) s_flag = 0;
  __syncthreads();
  int any = 0;
  for (int i = threadIdx.x; i < n; i += blockDim.x)
    if (i & 3) any |= (int)raw[i];
  if (any) atomicOr(&s_flag, 1);
  __syncthreads();
  int byte_mode = s_flag;
  const int* iraw = (const int*)raw;
  for (int i = threadIdx.x; i < n; i += blockDim.x) {
    int v = byte_mode ? (int)raw[i] : iraw[i];
    mout[i] = (v != 0) ? 1 : 0;
  }
}

// ---------------------------------------------------------------------------
// C[M,N] = act(A[M,K] @ W[N,K]^T + bias[N]); row-major, all dims %128==0, K%16==0.
// 128x128 tile, BK=16, 256 threads, 8x8 micro-tile (2x2 blocks of 4x4 at +64).
__global__ __launch_bounds__(256) void gemm_nt_kernel(
    const float* __restrict__ A, const float* __restrict__ W,
    const float* __restrict__ bias, float* __restrict__ C,
    int M, int N, int K, int relu) {
  __shared__ float As[16][128];
  __shared__ float Ws[16][128];
  int tid = threadIdx.x;
  int tx = tid & 15, ty = tid >> 4;
  size_t bm = (size_t)blockIdx.x * 128, bn = (size_t)blockIdx.y * 128;
  float acc[8][8];
#pragma unroll
  for (int i = 0; i < 8; ++i)
#pragma unroll
    for (int j = 0; j < 8; ++j) acc[i][j] = 0.0f;

  for (int k0 = 0; k0 < K; k0 += 16) {
#pragma unroll
    for (int p = 0; p < 2; ++p) {
      int id = p * 256 + tid;            // 0..511 -> 128 rows x 4 float4
      int row = id >> 2, kq = (id & 3) << 2;
      float4 a4 = *(const float4*)(A + (bm + row) * K + k0 + kq);
      float4 w4 = *(const float4*)(W + (bn + row) * K + k0 + kq);
      As[kq + 0][row] = a4.x; As[kq + 1][row] = a4.y;
      As[kq + 2][row] = a4.z; As[kq + 3][row] = a4.w;
      Ws[kq + 0][row] = w4.x; Ws[kq + 1][row] = w4.y;
      Ws[kq + 2][row] = w4.z; Ws[kq + 3][row] = w4.w;
    }
    __syncthreads();
#pragma unroll
    for (int k = 0; k < 16; ++k) {
      float4 a0 = *(const float4*)&As[k][ty * 4];
      float4 a1 = *(const float4*)&As[k][64 + ty * 4];
      float4 w0 = *(const float4*)&Ws[k][tx * 4];
      float4 w1 = *(const float4*)&Ws[k][64 + tx * 4];
      float av[8] = {a0.x, a0.y, a0.z, a0.w, a1.x, a1.y, a1.z, a1.w};
      float wv[8] = {w0.x, w0.y, w0.z, w0.w, w1.x, w1.y, w1.z, w1.w};
#pragma unroll
      for (int i = 0; i < 8; ++i)
#pragma unroll
        for (int j = 0; j < 8; ++j) acc[i][j] += av[i] * wv[j];
    }
    __syncthreads();
  }
  // epilogue
#pragma unroll
  for (int i = 0; i < 8; ++i) {
    size_t r = bm + (i < 4 ? (ty * 4 + i) : (64 + ty * 4 + (i - 4)));
#pragma unroll
    for (int jh = 0; jh < 2; ++jh) {
      size_t c = bn + jh * 64 + tx * 4;
      float o0 = acc[i][jh * 4 + 0] + bias[c + 0];
      float o1 = acc[i][jh * 4 + 1] + bias[c + 1];
      float o2 = acc[i][jh * 4 + 2] + bias[c + 2];
      float o3 = acc[i][jh * 4 + 3] + bias[c + 3];
      if (relu) {
        o0 = fmaxf(o0, 0.0f); o1 = fmaxf(o1, 0.0f);
        o2 = fmaxf(o2, 0.0f); o3 = fmaxf(o3, 0.0f);
      }
      float4 o = make_float4(o0, o1, o2, o3);
      *(float4*)(C + r * N + c) = o;
    }
  }
}

// ---------------------------------------------------------------------------
// Fused sign-attention. Block = (b, n, 64-row t-tile). 256 threads = 4 waves.
// lane_t = tid&63 (one t-row per lane, sq row held in 64 VGPRs);
// grp = tid>>6: s-quarter for the dot phase, h-quarter for PV.
// sk/v staged per 64-s chunk in LDS; sign written coalesced via LDS transpose;
// ctx (64x64) accumulated in registers, written via LDS transpose.
__global__ __launch_bounds__(256, 3) void attn_sign_kernel(
    const float* __restrict__ sqk,    // (B*T, 2048): cols [0,1024)=sq, [1024,2048)=sk (post-relu)
    const float* __restrict__ vbuf,   // (B*T, 1024)
    const int* __restrict__ maski,    // (B*T)
    float* __restrict__ sign_out,     // (B, N, T, T)
    float* __restrict__ ctx) {        // (B, T, D)
  __shared__ float sks[64][68];
  __shared__ float vs[64][68];
  __shared__ float sws[64][65];
  __shared__ int kms[64];

  int bid = blockIdx.x;
  int ntiles = T_ / 64;
  int tt = bid % ntiles;
  int bn = bid / ntiles;              // b*N_ + n
  int n = bn % N_;
  int b = bn / N_;
  int t0 = tt * 64;
  int tid = threadIdx.x;
  int lane_t = tid & 63;
  int grp = tid >> 6;

  // ---- load this lane's sq row (64 floats) into registers, staged via sks
#pragma unroll
  for (int p = 0; p < 4; ++p) {
    int r = p * 16 + (tid >> 4), f4 = tid & 15;
    *(float4*)&sks[r][f4 * 4] =
        *(const float4*)(sqk + ((size_t)(b * T_ + t0 + r)) * 2048 + n * H_ + f4 * 4);
  }
  __syncthreads();
  float sq[64];
#pragma unroll
  for (int h = 0; h < 64; ++h) sq[h] = sks[lane_t][h];
  __syncthreads();

  float cacc[16];
#pragma unroll
  for (int q = 0; q < 16; ++q) cacc[q] = 0.0f;

  for (int s0 = 0; s0 < T_; s0 += 64) {
    // ---- stage sk chunk + v chunk (coalesced 256B rows)
#pragma unroll
    for (int p = 0; p < 4; ++p) {
      int r = p * 16 + (tid >> 4), f4 = tid & 15;
      *(float4*)&sks[r][f4 * 4] =
          *(const float4*)(sqk + ((size_t)(b * T_ + s0 + r)) * 2048 + 1024 + n * H_ + f4 * 4);
      *(float4*)&vs[r][f4 * 4] =
          *(const float4*)(vbuf + ((size_t)(b * T_ + s0 + r)) * 1024 + n * H_ + f4 * 4);
    }
    if (tid < 64) kms[tid] = maski[b * T_ + s0 + tid];
    __syncthreads();

    // ---- dot phase: this wave computes s columns [grp*16, grp*16+16)
    float d[16];
#pragma unroll
    for (int i = 0; i < 16; ++i) d[i] = 0.0f;
#pragma unroll
    for (int h4 = 0; h4 < 16; ++h4) {
#pragma unroll
      for (int si = 0; si < 16; ++si) {
        float4 k4 = *(const float4*)&sks[grp * 16 + si][h4 * 4];  // wave-uniform
        d[si] += sq[h4 * 4 + 0] * k4.x + sq[h4 * 4 + 1] * k4.y +
                 sq[h4 * 4 + 2] * k4.z + sq[h4 * 4 + 3] * k4.w;
      }
    }

    // ---- tanh + mask, write sw tile (64t x 64s) to LDS
#pragma unroll
    for (int si = 0; si < 16; ++si) {
      int s = grp * 16 + si;
      sws[lane_t][s] = kms[s] ? 0.0f : fast_tanh(d[si]);
    }
    __syncthreads();

    // ---- coalesced sign_weight write-out (rows of 64 contiguous floats)
#pragma unroll
    for (int p = 0; p < 16; ++p) {
      int r = p * 4 + grp;
      sign_out[((size_t)bn * T_ + (t0 + r)) * T_ + s0 + lane_t] = sws[r][lane_t];
    }

    // ---- PV: ctx[lane_t][grp*16 .. +16) += sum_j sw[lane_t][j] * v[j][h]
#pragma unroll 4
    for (int j = 0; j < 64; ++j) {
      float w = sws[lane_t][j];
      float4 v0 = *(const float4*)&vs[j][grp * 16 + 0];
      float4 v1 = *(const float4*)&vs[j][grp * 16 + 4];
      float4 v2 = *(const float4*)&vs[j][grp * 16 + 8];
      float4 v3 = *(const float4*)&vs[j][grp * 16 + 12];
      cacc[0] += w * v0.x;  cacc[1] += w * v0.y;
      cacc[2] += w * v0.z;  cacc[3] += w * v0.w;
      cacc[4] += w * v1.x;  cacc[5] += w * v1.y;
      cacc[6] += w * v1.z;  cacc[7] += w * v1.w;
      cacc[8] += w * v2.x;  cacc[9] += w * v2.y;
      cacc[10] += w * v2.z; cacc[11] += w * v2.w;
      cacc[12] += w * v3.x; cacc[13] += w * v3.y;
      cacc[14] += w * v3.z; cacc[15] += w * v3.w;
    }
    __syncthreads();
  }

  // ---- ctx write-out via LDS transpose (coalesced 256B rows)
#pragma unroll
  for (int q = 0; q < 16; ++q) sws[lane_t][grp * 16 + q] = cacc[q];
  __syncthreads();
#pragma unroll
  for (int p = 0; p < 4; ++p) {
    int r = p * 16 + (tid >> 4), f4 = tid & 15;
    float4 o = make_float4(sws[r][f4 * 4 + 0], sws[r][f4 * 4 + 1],
                           sws[r][f4 * 4 + 2], sws[r][f4 * 4 + 3]);
    *(float4*)(ctx + ((size_t)(b * T_ + t0 + r)) * 1024 + n * H_ + f4 * 4) = o;
  }
}

// ---------------------------------------------------------------------------
extern "C" void kernel_launch(void* const* d_in, const int* in_sizes, int n_in,
                              void* d_out, int out_size, void* d_ws, size_t ws_size,
                              hipStream_t stream) {
  const float* x = (const float*)d_in[0];
  const unsigned char* kp = (const unsigned char*)d_in[1];
  const float* proj_w = (const float*)d_in[2];
  const float* proj_b = (const float*)d_in[3];
  const float* sign_w = (const float*)d_in[4];
  const float* sign_b = (const float*)d_in[5];
  const float* out_w = (const float*)d_in[6];
  const float* out_b = (const float*)d_in[7];

  float* out = (float*)d_out;                       // (B,T,D)
  float* sign_out = out + (size_t)B_ * T_ * D_;     // (B,N,T,T)

  float* ws = (float*)d_ws;
  float* sqk = ws;                                  // 8M floats (B*T x 2048)
  float* vbuf = ws + (size_t)8 * 1024 * 1024;       // 4M floats
  float* ctx = ws + (size_t)12 * 1024 * 1024;       // 4M floats
  int* maski = (int*)(ws + (size_t)16 * 1024 * 1024);

  const int M = B_ * T_;                            // 4096

  mask_expand_kernel<<<1, 256, 0, stream>>>(kp, maski, M);

  // sq|sk = relu(x @ sign_w^T + sign_b)   (4096 x 2048)
  {
    dim3 g(M / 128, 2048 / 128);
    gemm_nt_kernel<<<g, 256, 0, stream>>>(x, sign_w, sign_b, sqk, M, 2048, D_, 1);
  }
  // v = x @ proj_weight[D:2D]^T + proj_bias[D:2D]   (4096 x 1024)
  {
    dim3 g(M / 128, 1024 / 128);
    gemm_nt_kernel<<<g, 256, 0, stream>>>(x, proj_w + (size_t)D_ * D_, proj_b + D_,
                                          vbuf, M, D_, D_, 0);
  }
  // fused sign attention: sign_out + ctx
  attn_sign_kernel<<<B_ * N_ * (T_ / 64), 256, 0, stream>>>(sqk, vbuf, maski,
                                                            sign_out, ctx);
  // out = ctx @ out_w^T + out_b   (4096 x 1024)
  {
    dim3 g(M / 128, 1024 / 128);
    gemm_nt_kernel<<<g, 256, 0, stream>>>(ctx, out_w, out_b, out, M, D_, D_, 0);
  }
}

// Round 3
// 567.496 us; speedup vs baseline: 13.7610x; 13.7610x over previous
//
#include <hip/hip_runtime.h>

#define B_ 4
#define T_ 1024
#define D_ 1024
#define N_ 16
#define H_ 64

typedef __attribute__((ext_vector_type(8))) short bf16x8;
typedef __attribute__((ext_vector_type(4))) float f32x4;

// RNE float -> bf16
static __device__ __forceinline__ unsigned short f2bf(float f) {
  unsigned u = __float_as_uint(f);
  u += 0x7fff + ((u >> 16) & 1);
  return (unsigned short)(u >> 16);
}

// tanh(x) = 1 - 2/(exp(2x)+1); stable at both ends
static __device__ __forceinline__ float fast_tanh(float x) {
  float e = __expf(2.0f * x);
  return 1.0f - 2.0f / (e + 1.0f);
}

// ---------------------------------------------------------------------------
// Mask expand (bool-dtype auto-detect, deterministic; validated in round 1).
__global__ void mask_expand_kernel(const unsigned char* __restrict__ raw,
                                   int* __restrict__ mout, int n) {
  __shared__ int s_flag;
  if (threadIdx.x == 0) s_flag = 0;
  __syncthreads();
  int any = 0;
  for (int i = threadIdx.x; i < n; i += blockDim.x)
    if (i & 3) any |= (int)raw[i];
  if (any) atomicOr(&s_flag, 1);
  __syncthreads();
  int byte_mode = s_flag;
  const int* iraw = (const int*)raw;
  for (int i = threadIdx.x; i < n; i += blockDim.x) {
    int v = byte_mode ? (int)raw[i] : iraw[i];
    mout[i] = (v != 0) ? 1 : 0;
  }
}

// ---------------------------------------------------------------------------
// C = act(A[M,K] @ W[N,K]^T + bias); fp32 VALU GEMM (validated round 1).
// out_mode: 0 = fp32 row-major; 1 = bf16 row-major; 2 = bf16 "vt" transpose:
//   Cb[(b*1024 + c)*1024 + t] with r = b*1024+t (requires M=4096 multiple).
__global__ __launch_bounds__(256) void gemm_nt_kernel(
    const float* __restrict__ A, const float* __restrict__ W,
    const float* __restrict__ bias, void* __restrict__ Cv,
    int M, int N, int K, int relu, int out_mode) {
  __shared__ float As[16][128];
  __shared__ float Ws[16][128];
  int tid = threadIdx.x;
  int tx = tid & 15, ty = tid >> 4;
  size_t bm = (size_t)blockIdx.x * 128, bn = (size_t)blockIdx.y * 128;
  float acc[8][8];
#pragma unroll
  for (int i = 0; i < 8; ++i)
#pragma unroll
    for (int j = 0; j < 8; ++j) acc[i][j] = 0.0f;

  for (int k0 = 0; k0 < K; k0 += 16) {
#pragma unroll
    for (int p = 0; p < 2; ++p) {
      int id = p * 256 + tid;
      int row = id >> 2, kq = (id & 3) << 2;
      float4 a4 = *(const float4*)(A + (bm + row) * K + k0 + kq);
      float4 w4 = *(const float4*)(W + (bn + row) * K + k0 + kq);
      As[kq + 0][row] = a4.x; As[kq + 1][row] = a4.y;
      As[kq + 2][row] = a4.z; As[kq + 3][row] = a4.w;
      Ws[kq + 0][row] = w4.x; Ws[kq + 1][row] = w4.y;
      Ws[kq + 2][row] = w4.z; Ws[kq + 3][row] = w4.w;
    }
    __syncthreads();
#pragma unroll
    for (int k = 0; k < 16; ++k) {
      float4 a0 = *(const float4*)&As[k][ty * 4];
      float4 a1 = *(const float4*)&As[k][64 + ty * 4];
      float4 w0 = *(const float4*)&Ws[k][tx * 4];
      float4 w1 = *(const float4*)&Ws[k][64 + tx * 4];
      float av[8] = {a0.x, a0.y, a0.z, a0.w, a1.x, a1.y, a1.z, a1.w};
      float wv[8] = {w0.x, w0.y, w0.z, w0.w, w1.x, w1.y, w1.z, w1.w};
#pragma unroll
      for (int i = 0; i < 8; ++i)
#pragma unroll
        for (int j = 0; j < 8; ++j) acc[i][j] += av[i] * wv[j];
    }
    __syncthreads();
  }
#pragma unroll
  for (int i = 0; i < 8; ++i) {
    size_t r = bm + (i < 4 ? (ty * 4 + i) : (64 + ty * 4 + (i - 4)));
#pragma unroll
    for (int jh = 0; jh < 2; ++jh) {
      size_t c = bn + jh * 64 + tx * 4;
      float o[4];
#pragma unroll
      for (int q = 0; q < 4; ++q) o[q] = acc[i][jh * 4 + q] + bias[c + q];
      if (relu) {
#pragma unroll
        for (int q = 0; q < 4; ++q) o[q] = fmaxf(o[q], 0.0f);
      }
      if (out_mode == 0) {
        float4 o4 = make_float4(o[0], o[1], o[2], o[3]);
        *(float4*)((float*)Cv + r * N + c) = o4;
      } else if (out_mode == 1) {
        unsigned short* Cb = (unsigned short*)Cv;
        uint2 pk;
        pk.x = (unsigned)f2bf(o[0]) | ((unsigned)f2bf(o[1]) << 16);
        pk.y = (unsigned)f2bf(o[2]) | ((unsigned)f2bf(o[3]) << 16);
        *(uint2*)(Cb + r * N + c) = pk;
      } else {
        unsigned short* Cb = (unsigned short*)Cv;
        size_t bb = (r >> 10) << 10, t = r & 1023;
#pragma unroll
        for (int q = 0; q < 4; ++q)
          Cb[(bb + c + q) * 1024 + t] = f2bf(o[q]);
      }
    }
  }
}

// ---------------------------------------------------------------------------
// Fused sign-attention, bf16 MFMA (16x16x32, verified layouts).
// Block = (b, n, 128-row t-tile); 4 waves, each owns 32 t-rows.
// Per 64-s chunk: stage SK (row-major [s][64], XOR-swz) + Vt ([h][s], XOR-swz);
// QK^T via mfma (A=SQ hoisted in regs from global, B=SK); tanh+mask -> SW fp32
// global write; P -> bf16 -> per-wave LDS (XOR-swz); PV via mfma (A=P, B=Vt)
// accumulating ctx in VGPRs; ctx written fp32 at end.
__global__ __launch_bounds__(256, 2) void attn_mfma_kernel(
    const unsigned short* __restrict__ sqkb,  // (4096,2048) bf16: sq | sk
    const unsigned short* __restrict__ vtb,   // (4096,1024) bf16: row=b*1024+n*64+h, col=t
    const int* __restrict__ maski,            // (4096)
    float* __restrict__ sign_out,             // (B,N,T,T) fp32
    float* __restrict__ ctx) {                // (B,T,D) fp32
  __shared__ __align__(16) char sk_lds[64 * 128];       // [s][64 bf16] swz
  __shared__ __align__(16) char vt_lds[64 * 128];       // [h][64 bf16] swz
  __shared__ __align__(16) char p_lds[4 * 32 * 128];    // per-wave [t][64 bf16] swz
  __shared__ int kms[64];

  int bid = blockIdx.x;
  int tt = bid & 7;
  int bn = bid >> 3;
  int n = bn & 15, b = bn >> 4;
  int t0 = tt * 128;
  int tid = threadIdx.x;
  int l = tid & 63, w = tid >> 6;
  int l15 = l & 15, l4 = l >> 4;

  // hoist SQ A-frags: A[row=t][k], row=l&15, k=(l>>4)*8+i (verified layout)
  bf16x8 aq[2][2];
#pragma unroll
  for (int mt = 0; mt < 2; ++mt)
#pragma unroll
    for (int ks = 0; ks < 2; ++ks)
      aq[mt][ks] = *(const bf16x8*)(sqkb +
          (size_t)(b * 1024 + t0 + w * 32 + mt * 16 + l15) * 2048 +
          n * 64 + ks * 32 + l4 * 8);

  f32x4 cacc[2][4];
#pragma unroll
  for (int mt = 0; mt < 2; ++mt)
#pragma unroll
    for (int ht = 0; ht < 4; ++ht) cacc[mt][ht] = (f32x4){0.f, 0.f, 0.f, 0.f};

  for (int s0 = 0; s0 < T_; s0 += 64) {
    __syncthreads();  // prev chunk fully consumed before restage
#pragma unroll
    for (int p = 0; p < 2; ++p) {
      int seg = p * 256 + tid;
      int row = seg >> 3, sk16 = seg & 7;
      int swz = (sk16 * 16) ^ ((row & 7) << 4);
      float4 dsk = *(const float4*)(sqkb +
          (size_t)(b * 1024 + s0 + row) * 2048 + 1024 + n * 64 + sk16 * 8);
      *(float4*)(sk_lds + row * 128 + swz) = dsk;
      float4 dvt = *(const float4*)(vtb +
          (size_t)(bn * 64 + row) * 1024 + s0 + sk16 * 8);
      *(float4*)(vt_lds + row * 128 + swz) = dvt;
    }
    if (tid < 64) kms[tid] = maski[b * 1024 + s0 + tid];
    __syncthreads();

    // ---- QK^T
    f32x4 pacc[2][4];
#pragma unroll
    for (int mt = 0; mt < 2; ++mt)
#pragma unroll
      for (int st = 0; st < 4; ++st) pacc[mt][st] = (f32x4){0.f, 0.f, 0.f, 0.f};
#pragma unroll
    for (int ks = 0; ks < 2; ++ks) {
#pragma unroll
      for (int st = 0; st < 4; ++st) {
        int srow = st * 16 + l15;
        bf16x8 bk = *(const bf16x8*)(sk_lds + srow * 128 +
            (((ks * 32 + l4 * 8) * 2) ^ ((srow & 7) << 4)));
#pragma unroll
        for (int mt = 0; mt < 2; ++mt)
          pacc[mt][st] = __builtin_amdgcn_mfma_f32_16x16x32_bf16(
              aq[mt][ks], bk, pacc[mt][st], 0, 0, 0);
      }
    }

    // ---- tanh + mask; SW fp32 out; P bf16 -> LDS
#pragma unroll
    for (int mt = 0; mt < 2; ++mt)
#pragma unroll
      for (int st = 0; st < 4; ++st) {
        int s = st * 16 + l15;
        int m = kms[s];
#pragma unroll
        for (int r = 0; r < 4; ++r) {
          int trow = mt * 16 + l4 * 4 + r;
          float v = m ? 0.0f : fast_tanh(pacc[mt][st][r]);
          sign_out[((size_t)bn * 1024 + t0 + w * 32 + trow) * 1024 + s0 + s] = v;
          *(unsigned short*)(p_lds + w * 4096 + trow * 128 +
                             ((s * 2) ^ ((trow & 7) << 4))) = f2bf(v);
        }
      }

    // ---- PV (wave-local P; compiler orders LDS write->read)
#pragma unroll
    for (int ks = 0; ks < 2; ++ks) {
      bf16x8 aP[2];
#pragma unroll
      for (int mt = 0; mt < 2; ++mt) {
        int trow = mt * 16 + l15;
        aP[mt] = *(const bf16x8*)(p_lds + w * 4096 + trow * 128 +
            (((ks * 32 + l4 * 8) * 2) ^ ((trow & 7) << 4)));
      }
#pragma unroll
      for (int ht = 0; ht < 4; ++ht) {
        int hrow = ht * 16 + l15;
        bf16x8 bV = *(const bf16x8*)(vt_lds + hrow * 128 +
            (((ks * 32 + l4 * 8) * 2) ^ ((hrow & 7) << 4)));
#pragma unroll
        for (int mt = 0; mt < 2; ++mt)
          cacc[mt][ht] = __builtin_amdgcn_mfma_f32_16x16x32_bf16(
              aP[mt], bV, cacc[mt][ht], 0, 0, 0);
      }
    }
  }

  // ---- ctx fp32 write (64B segments per quarter-wave)
#pragma unroll
  for (int mt = 0; mt < 2; ++mt)
#pragma unroll
    for (int ht = 0; ht < 4; ++ht)
#pragma unroll
      for (int r = 0; r < 4; ++r)
        ctx[((size_t)(b * 1024 + t0 + w * 32 + mt * 16 + l4 * 4 + r)) * 1024 +
            n * 64 + ht * 16 + l15] = cacc[mt][ht][r];
}

// ---------------------------------------------------------------------------
extern "C" void kernel_launch(void* const* d_in, const int* in_sizes, int n_in,
                              void* d_out, int out_size, void* d_ws, size_t ws_size,
                              hipStream_t stream) {
  const float* x = (const float*)d_in[0];
  const unsigned char* kp = (const unsigned char*)d_in[1];
  const float* proj_w = (const float*)d_in[2];
  const float* proj_b = (const float*)d_in[3];
  const float* sign_w = (const float*)d_in[4];
  const float* sign_b = (const float*)d_in[5];
  const float* out_w = (const float*)d_in[6];
  const float* out_b = (const float*)d_in[7];

  float* out = (float*)d_out;                    // (B,T,D) fp32
  float* sign_out = out + (size_t)B_ * T_ * D_;  // (B,N,T,T) fp32

  char* ws = (char*)d_ws;
  unsigned short* sqkb = (unsigned short*)ws;                       // 16 MB
  unsigned short* vtb = (unsigned short*)(ws + ((size_t)16 << 20)); // 8 MB
  float* ctx = (float*)(ws + ((size_t)24 << 20));                   // 16 MB
  int* maski = (int*)(ws + ((size_t)40 << 20));                     // 16 KB

  const int M = B_ * T_;  // 4096

  mask_expand_kernel<<<1, 256, 0, stream>>>(kp, maski, M);

  // sq|sk = relu(x @ sign_w^T + sign_b) -> bf16 (4096 x 2048)
  {
    dim3 g(M / 128, 2048 / 128);
    gemm_nt_kernel<<<g, 256, 0, stream>>>(x, sign_w, sign_b, sqkb, M, 2048, D_, 1, 1);
  }
  // vt = (x @ proj_w[D:2D]^T + proj_b[D:2D]) transposed -> bf16 (4096 x 1024)
  {
    dim3 g(M / 128, 1024 / 128);
    gemm_nt_kernel<<<g, 256, 0, stream>>>(x, proj_w + (size_t)D_ * D_, proj_b + D_,
                                          vtb, M, D_, D_, 0, 2);
  }
  // fused sign attention (MFMA): sign_out fp32 + ctx fp32
  attn_mfma_kernel<<<B_ * N_ * (T_ / 128), 256, 0, stream>>>(sqkb, vtb, maski,
                                                             sign_out, ctx);
  // out = ctx @ out_w^T + out_b (fp32)
  {
    dim3 g(M / 128, 1024 / 128);
    gemm_nt_kernel<<<g, 256, 0, stream>>>(ctx, out_w, out_b, out, M, D_, D_, 0, 0);
  }
}

// Round 4
// 213.322 us; speedup vs baseline: 36.6079x; 2.6603x over previous
//
#include <hip/hip_runtime.h>

#define B_ 4
#define T_ 1024
#define D_ 1024
#define N_ 16
#define H_ 64

typedef __attribute__((ext_vector_type(8))) short bf16x8;
typedef __attribute__((ext_vector_type(4))) float f32x4;

// RNE float -> bf16
static __device__ __forceinline__ unsigned short f2bf(float f) {
  unsigned u = __float_as_uint(f);
  u += 0x7fff + ((u >> 16) & 1);
  return (unsigned short)(u >> 16);
}

// tanh(x) = 1 - 2/(exp(2x)+1); stable at both ends
static __device__ __forceinline__ float fast_tanh(float x) {
  float e = __expf(2.0f * x);
  return 1.0f - 2.0f / (e + 1.0f);
}

// ---------------------------------------------------------------------------
// Mask expand (bool-dtype auto-detect, deterministic; validated round 1).
__global__ void mask_expand_kernel(const unsigned char* __restrict__ raw,
                                   int* __restrict__ mout, int n) {
  __shared__ int s_flag;
  if (threadIdx.x == 0) s_flag = 0;
  __syncthreads();
  int any = 0;
  for (int i = threadIdx.x; i < n; i += blockDim.x)
    if (i & 3) any |= (int)raw[i];
  if (any) atomicOr(&s_flag, 1);
  __syncthreads();
  int byte_mode = s_flag;
  const int* iraw = (const int*)raw;
  for (int i = threadIdx.x; i < n; i += blockDim.x) {
    int v = byte_mode ? (int)raw[i] : iraw[i];
    mout[i] = (v != 0) ? 1 : 0;
  }
}

// ---------------------------------------------------------------------------
// fp32 -> bf16 cast, 4 elems/thread
__global__ void cast_f2b_kernel(const float* __restrict__ in,
                                unsigned short* __restrict__ out, int n4) {
  int i = blockIdx.x * blockDim.x + threadIdx.x;
  if (i < n4) {
    float4 v = ((const float4*)in)[i];
    uint2 pk;
    pk.x = (unsigned)f2bf(v.x) | ((unsigned)f2bf(v.y) << 16);
    pk.y = (unsigned)f2bf(v.z) | ((unsigned)f2bf(v.w) << 16);
    ((uint2*)out)[i] = pk;
  }
}

// ---------------------------------------------------------------------------
// bf16 MFMA GEMM, m97 structure: 128x128 tile, BK=64, 4 waves (2x2), each wave
// a 64x64 output (4x4 frags of 16x16x32), linear LDS + global_load_lds w=16,
// 2-barrier K-loop. C = act(A[M,K] @ W[N,K]^T + bias).
// out_mode: 0 = fp32 row-major; 1 = bf16 row-major; 2 = bf16 "vt" transpose
//   Cb[(bbase + c)*1024 + t] (batches of 1024 rows; BM=128 divides 1024).
__global__ __launch_bounds__(256, 2) void gemm_mfma_kernel(
    const unsigned short* __restrict__ A,  // (M,K) bf16 row-major
    const unsigned short* __restrict__ W,  // (N,K) bf16 row-major
    const float* __restrict__ bias,        // (N) fp32
    void* __restrict__ Cv,
    int M, int N, int K, int relu, int out_mode) {
  __shared__ __align__(16) unsigned short As[128 * 64];
  __shared__ __align__(16) unsigned short Ws[128 * 64];
  int tid = threadIdx.x;
  int l = tid & 63, w = tid >> 6;
  int l15 = l & 15, l4 = l >> 4;
  int wr = w >> 1, wc = w & 1;
  size_t bm = (size_t)blockIdx.x * 128, bn = (size_t)blockIdx.y * 128;

  f32x4 acc[4][4];
#pragma unroll
  for (int m = 0; m < 4; ++m)
#pragma unroll
    for (int n = 0; n < 4; ++n) acc[m][n] = (f32x4){0.f, 0.f, 0.f, 0.f};

  for (int k0 = 0; k0 < K; k0 += 64) {
    __syncthreads();
#pragma unroll
    for (int i = 0; i < 4; ++i) {
      int seg = i * 256 + tid;             // 0..1023 16B segments
      int row = seg >> 3, cb = (seg & 7) << 4;
      // wave-uniform LDS base; HW adds lane*16
      unsigned short* lA = As + (size_t)(i * 256 + w * 64) * 8;
      unsigned short* lW = Ws + (size_t)(i * 256 + w * 64) * 8;
      __builtin_amdgcn_global_load_lds(
          (const __attribute__((address_space(1))) void*)
              ((const char*)(A + (bm + row) * K + k0) + cb),
          (__attribute__((address_space(3))) void*)lA, 16, 0, 0);
      __builtin_amdgcn_global_load_lds(
          (const __attribute__((address_space(1))) void*)
              ((const char*)(W + (bn + row) * K + k0) + cb),
          (__attribute__((address_space(3))) void*)lW, 16, 0, 0);
    }
    __syncthreads();

#pragma unroll
    for (int ks = 0; ks < 2; ++ks) {
      bf16x8 af[4], bf[4];
#pragma unroll
      for (int m = 0; m < 4; ++m)
        af[m] = *(const bf16x8*)(As + (wr * 64 + m * 16 + l15) * 64 +
                                 ks * 32 + l4 * 8);
#pragma unroll
      for (int n = 0; n < 4; ++n)
        bf[n] = *(const bf16x8*)(Ws + (wc * 64 + n * 16 + l15) * 64 +
                                 ks * 32 + l4 * 8);
#pragma unroll
      for (int m = 0; m < 4; ++m)
#pragma unroll
        for (int n = 0; n < 4; ++n)
          acc[m][n] = __builtin_amdgcn_mfma_f32_16x16x32_bf16(
              af[m], bf[n], acc[m][n], 0, 0, 0);
    }
  }

  // ---- epilogue
#pragma unroll
  for (int n = 0; n < 4; ++n) {
    size_t c = bn + wc * 64 + n * 16 + l15;
    float bv = bias[c];
#pragma unroll
    for (int m = 0; m < 4; ++m) {
      float o[4];
#pragma unroll
      for (int rr = 0; rr < 4; ++rr) {
        o[rr] = acc[m][n][rr] + bv;
        if (relu) o[rr] = fmaxf(o[rr], 0.0f);
      }
      size_t r0 = bm + wr * 64 + m * 16 + l4 * 4;
      if (out_mode == 0) {
        float* C = (float*)Cv;
#pragma unroll
        for (int rr = 0; rr < 4; ++rr) C[(r0 + rr) * N + c] = o[rr];
      } else if (out_mode == 1) {
        unsigned short* Cb = (unsigned short*)Cv;
#pragma unroll
        for (int rr = 0; rr < 4; ++rr) Cb[(r0 + rr) * N + c] = f2bf(o[rr]);
      } else {
        unsigned short* Cb = (unsigned short*)Cv;
        size_t bbase = (bm >> 10) << 10;
        int tloc = (int)(bm & 1023) + wr * 64 + m * 16 + l4 * 4;
        uint2 pk;
        pk.x = (unsigned)f2bf(o[0]) | ((unsigned)f2bf(o[1]) << 16);
        pk.y = (unsigned)f2bf(o[2]) | ((unsigned)f2bf(o[3]) << 16);
        *(uint2*)(Cb + (bbase + c) * 1024 + tloc) = pk;
      }
    }
  }
}

// ---------------------------------------------------------------------------
// Fused sign-attention, bf16 MFMA (validated round 3); ctx now written bf16.
__global__ __launch_bounds__(256, 2) void attn_mfma_kernel(
    const unsigned short* __restrict__ sqkb,  // (4096,2048) bf16: sq | sk
    const unsigned short* __restrict__ vtb,   // (4096,1024) bf16 vt
    const int* __restrict__ maski,            // (4096)
    float* __restrict__ sign_out,             // (B,N,T,T) fp32
    unsigned short* __restrict__ ctx) {       // (B,T,D) bf16
  __shared__ __align__(16) char sk_lds[64 * 128];
  __shared__ __align__(16) char vt_lds[64 * 128];
  __shared__ __align__(16) char p_lds[4 * 32 * 128];
  __shared__ int kms[64];

  int bid = blockIdx.x;
  int tt = bid & 7;
  int bn = bid >> 3;
  int n = bn & 15, b = bn >> 4;
  int t0 = tt * 128;
  int tid = threadIdx.x;
  int l = tid & 63, w = tid >> 6;
  int l15 = l & 15, l4 = l >> 4;

  bf16x8 aq[2][2];
#pragma unroll
  for (int mt = 0; mt < 2; ++mt)
#pragma unroll
    for (int ks = 0; ks < 2; ++ks)
      aq[mt][ks] = *(const bf16x8*)(sqkb +
          (size_t)(b * 1024 + t0 + w * 32 + mt * 16 + l15) * 2048 +
          n * 64 + ks * 32 + l4 * 8);

  f32x4 cacc[2][4];
#pragma unroll
  for (int mt = 0; mt < 2; ++mt)
#pragma unroll
    for (int ht = 0; ht < 4; ++ht) cacc[mt][ht] = (f32x4){0.f, 0.f, 0.f, 0.f};

  for (int s0 = 0; s0 < T_; s0 += 64) {
    __syncthreads();
#pragma unroll
    for (int p = 0; p < 2; ++p) {
      int seg = p * 256 + tid;
      int row = seg >> 3, sk16 = seg & 7;
      int swz = (sk16 * 16) ^ ((row & 7) << 4);
      float4 dsk = *(const float4*)(sqkb +
          (size_t)(b * 1024 + s0 + row) * 2048 + 1024 + n * 64 + sk16 * 8);
      *(float4*)(sk_lds + row * 128 + swz) = dsk;
      float4 dvt = *(const float4*)(vtb +
          (size_t)(bn * 64 + row) * 1024 + s0 + sk16 * 8);
      *(float4*)(vt_lds + row * 128 + swz) = dvt;
    }
    if (tid < 64) kms[tid] = maski[b * 1024 + s0 + tid];
    __syncthreads();

    // ---- QK^T
    f32x4 pacc[2][4];
#pragma unroll
    for (int mt = 0; mt < 2; ++mt)
#pragma unroll
      for (int st = 0; st < 4; ++st) pacc[mt][st] = (f32x4){0.f, 0.f, 0.f, 0.f};
#pragma unroll
    for (int ks = 0; ks < 2; ++ks) {
#pragma unroll
      for (int st = 0; st < 4; ++st) {
        int srow = st * 16 + l15;
        bf16x8 bk = *(const bf16x8*)(sk_lds + srow * 128 +
            (((ks * 32 + l4 * 8) * 2) ^ ((srow & 7) << 4)));
#pragma unroll
        for (int mt = 0; mt < 2; ++mt)
          pacc[mt][st] = __builtin_amdgcn_mfma_f32_16x16x32_bf16(
              aq[mt][ks], bk, pacc[mt][st], 0, 0, 0);
      }
    }

    // ---- tanh + mask; SW fp32 out; P bf16 -> LDS
#pragma unroll
    for (int mt = 0; mt < 2; ++mt)
#pragma unroll
      for (int st = 0; st < 4; ++st) {
        int s = st * 16 + l15;
        int m = kms[s];
#pragma unroll
        for (int r = 0; r < 4; ++r) {
          int trow = mt * 16 + l4 * 4 + r;
          float v = m ? 0.0f : fast_tanh(pacc[mt][st][r]);
          sign_out[((size_t)bn * 1024 + t0 + w * 32 + trow) * 1024 + s0 + s] = v;
          *(unsigned short*)(p_lds + w * 4096 + trow * 128 +
                             ((s * 2) ^ ((trow & 7) << 4))) = f2bf(v);
        }
      }

    // ---- PV
#pragma unroll
    for (int ks = 0; ks < 2; ++ks) {
      bf16x8 aP[2];
#pragma unroll
      for (int mt = 0; mt < 2; ++mt) {
        int trow = mt * 16 + l15;
        aP[mt] = *(const bf16x8*)(p_lds + w * 4096 + trow * 128 +
            (((ks * 32 + l4 * 8) * 2) ^ ((trow & 7) << 4)));
      }
#pragma unroll
      for (int ht = 0; ht < 4; ++ht) {
        int hrow = ht * 16 + l15;
        bf16x8 bV = *(const bf16x8*)(vt_lds + hrow * 128 +
            (((ks * 32 + l4 * 8) * 2) ^ ((hrow & 7) << 4)));
#pragma unroll
        for (int mt = 0; mt < 2; ++mt)
          cacc[mt][ht] = __builtin_amdgcn_mfma_f32_16x16x32_bf16(
              aP[mt], bV, cacc[mt][ht], 0, 0, 0);
      }
    }
  }

  // ---- ctx bf16 write
#pragma unroll
  for (int mt = 0; mt < 2; ++mt)
#pragma unroll
    for (int ht = 0; ht < 4; ++ht)
#pragma unroll
      for (int r = 0; r < 4; ++r)
        ctx[((size_t)(b * 1024 + t0 + w * 32 + mt * 16 + l4 * 4 + r)) * 1024 +
            n * 64 + ht * 16 + l15] = f2bf(cacc[mt][ht][r]);
}

// ---------------------------------------------------------------------------
extern "C" void kernel_launch(void* const* d_in, const int* in_sizes, int n_in,
                              void* d_out, int out_size, void* d_ws, size_t ws_size,
                              hipStream_t stream) {
  const float* x = (const float*)d_in[0];
  const unsigned char* kp = (const unsigned char*)d_in[1];
  const float* proj_w = (const float*)d_in[2];
  const float* proj_b = (const float*)d_in[3];
  const float* sign_w = (const float*)d_in[4];
  const float* sign_b = (const float*)d_in[5];
  const float* out_w = (const float*)d_in[6];
  const float* out_b = (const float*)d_in[7];

  float* out = (float*)d_out;                    // (B,T,D) fp32
  float* sign_out = out + (size_t)B_ * T_ * D_;  // (B,N,T,T) fp32

  char* ws = (char*)d_ws;
  unsigned short* xb   = (unsigned short*)ws;                        // 8 MB (aliased by ctxb later)
  unsigned short* swb  = (unsigned short*)(ws + ((size_t)8 << 20));  // 4 MB
  unsigned short* pwb  = (unsigned short*)(ws + ((size_t)12 << 20)); // 2 MB
  unsigned short* owb  = (unsigned short*)(ws + ((size_t)14 << 20)); // 2 MB
  unsigned short* sqkb = (unsigned short*)(ws + ((size_t)16 << 20)); // 16 MB
  unsigned short* vtb  = (unsigned short*)(ws + ((size_t)32 << 20)); // 8 MB
  int* maski = (int*)(ws + ((size_t)40 << 20));                      // 16 KB
  unsigned short* ctxb = xb;  // xb dead after v-GEMM; attn runs after

  const int M = B_ * T_;  // 4096

  mask_expand_kernel<<<1, 256, 0, stream>>>(kp, maski, M);

  // bf16 casts: x, sign_w, proj_w[D:2D], out_w
  cast_f2b_kernel<<<(M * D_ / 4 + 255) / 256, 256, 0, stream>>>(x, xb, M * D_ / 4);
  cast_f2b_kernel<<<(2 * D_ * D_ / 4 + 255) / 256, 256, 0, stream>>>(sign_w, swb,
                                                                     2 * D_ * D_ / 4);
  cast_f2b_kernel<<<(D_ * D_ / 4 + 255) / 256, 256, 0, stream>>>(
      proj_w + (size_t)D_ * D_, pwb, D_ * D_ / 4);
  cast_f2b_kernel<<<(D_ * D_ / 4 + 255) / 256, 256, 0, stream>>>(out_w, owb,
                                                                 D_ * D_ / 4);

  // sq|sk = relu(x @ sign_w^T + sign_b) -> bf16 (4096 x 2048)
  {
    dim3 g(M / 128, 2048 / 128);
    gemm_mfma_kernel<<<g, 256, 0, stream>>>(xb, swb, sign_b, sqkb, M, 2048, D_, 1, 1);
  }
  // vt = (x @ proj_w[D:2D]^T + proj_b[D:2D])^T -> bf16 (per-batch transpose)
  {
    dim3 g(M / 128, 1024 / 128);
    gemm_mfma_kernel<<<g, 256, 0, stream>>>(xb, pwb, proj_b + D_, vtb, M, D_, D_, 0, 2);
  }
  // fused sign attention (MFMA): sign_out fp32 + ctx bf16
  attn_mfma_kernel<<<B_ * N_ * (T_ / 128), 256, 0, stream>>>(sqkb, vtb, maski,
                                                             sign_out, ctxb);
  // out = ctx @ out_w^T + out_b (fp32 out)
  {
    dim3 g(M / 128, 1024 / 128);
    gemm_mfma_kernel<<<g, 256, 0, stream>>>(ctxb, owb, out_b, out, M, D_, D_, 0, 0);
  }
}